// Round 5
// baseline (787.418 us; speedup 1.0000x reference)
//
#include <hip/hip_runtime.h>
#include <math.h>

// node1 [N,1,128] f32, node2 [N,32,128] f32, N=50000.
// logit[n] = dot(node1[n], sum_m node2[n,m,:]); out = softmax(logit over n).
//
// Structure (R1-proven main loop, one node per wave):
//   K1: logits + per-block exp partials; LAST block (atomic counter) reduces
//       the 12500 double partials in fixed order -> logS (deterministic).
//   K2: out[i] = expf(logit[i] - logS).
// Softmax without a max pass: logits ~N(0,64^2), max ~ +300 << 709, so
// exp((double)l) cannot overflow.

typedef float f32x4 __attribute__((ext_vector_type(4)));

#define D4   32     // 128 floats = 32 float4 per node1 row
#define N2F4 1024   // 32*128 floats = 1024 float4 per node2 slab

// ---- Kernel 1: per-node fused sum+dot -> logits, psum, last-block logS ----
// One wave (64 lanes) per node; 4 waves per 256-thread block.
__global__ __launch_bounds__(256) void logits_kernel(
    const f32x4* __restrict__ n1,    // [N][32] f32x4
    const f32x4* __restrict__ n2,    // [N][1024] f32x4
    float*  __restrict__ logits,     // [N]
    double* __restrict__ psum,       // [gridDim.x] partial sums of exp(logit)
    double* __restrict__ stats,      // [1] -> logS
    int*    __restrict__ counter,    // [1], zeroed by hipMemsetAsync pre-launch
    int N)
{
    __shared__ double se[4];
    __shared__ int slast;
    const int tid  = threadIdx.x;
    const int wave = tid >> 6;
    const int lane = tid & 63;
    const int n = blockIdx.x * 4 + wave;

    double e = 0.0;
    if (n < N) {
        const f32x4* __restrict__ a = n1 + (size_t)n * D4;
        const f32x4* __restrict__ b = n2 + (size_t)n * N2F4;

        const f32x4 av = a[lane & 31];   // 64 lanes cover 32 float4s twice

        float acc = 0.0f;
#pragma unroll
        for (int i = 0; i < 16; ++i) {
            // node2 is streamed exactly once -> non-temporal
            const f32x4 bv = __builtin_nontemporal_load(&b[lane + i * 64]);
            acc += av.x * bv.x + av.y * bv.y + av.z * bv.z + av.w * bv.w;
        }

#pragma unroll
        for (int off = 32; off > 0; off >>= 1)
            acc += __shfl_down(acc, off);

        if (lane == 0) {
            logits[n] = acc;
            e = exp((double)acc);
        }
    }
    if (lane == 0) se[wave] = e;
    __syncthreads();
    if (tid == 0) {
        psum[blockIdx.x] = (se[0] + se[1]) + (se[2] + se[3]);
        __threadfence();                       // publish psum before counting
        int old = atomicAdd(counter, 1);       // device-scope
        slast = (old == (int)gridDim.x - 1);
    }
    __syncthreads();

    if (slast) {
        // last-arriving block: fixed-order reduce of all partials (deterministic)
        __shared__ double sred[4];
        __threadfence();                       // acquire: see all psum writes
        double s = 0.0;
        const int nb = gridDim.x;
        for (int i = tid; i < nb; i += 256) s += psum[i];
#pragma unroll
        for (int off = 32; off > 0; off >>= 1) s += __shfl_down(s, off);
        if (lane == 0) sred[wave] = s;
        __syncthreads();
        if (tid == 0) {
            double tot = (sred[0] + sred[1]) + (sred[2] + sred[3]);
            stats[0] = log(tot);
        }
    }
}

// ---- Kernel 2: normalize -> output ----
__global__ __launch_bounds__(256) void scale_kernel(
    const float* __restrict__ logits, const double* __restrict__ stats,
    float* __restrict__ out, int N)
{
    const float logS = (float)stats[0];
    for (int i = blockIdx.x * 256 + threadIdx.x; i < N; i += gridDim.x * 256)
        out[i] = expf(logits[i] - logS);
}

extern "C" void kernel_launch(void* const* d_in, const int* in_sizes, int n_in,
                              void* d_out, int out_size, void* d_ws, size_t ws_size,
                              hipStream_t stream)
{
    const f32x4* n1 = (const f32x4*)d_in[0];   // [N,1,128] f32
    const f32x4* n2 = (const f32x4*)d_in[1];   // [N,32,128] f32
    float* out = (float*)d_out;                // [N] f32

    const int N = out_size;                    // 50000
    const int blocks1 = (N + 3) / 4;           // 12500, one node per wave

    // ws layout: logits (N f32) | psum (blocks1 f64) | stats (1 f64) | counter (int)
    float*  logits = (float*)d_ws;
    char*   base   = (char*)d_ws;
    size_t  off    = ((size_t)N * sizeof(float) + 7) & ~(size_t)7;
    double* psum   = (double*)(base + off);
    double* stats  = psum + blocks1;
    int*    counter = (int*)(stats + 1);

    hipMemsetAsync(counter, 0, sizeof(int), stream);   // graph-capturable
    logits_kernel<<<blocks1, 256, 0, stream>>>(n1, n2, logits, psum, stats, counter, N);
    const int blocks2 = (N + 255) / 256;
    scale_kernel<<<blocks2, 256, 0, stream>>>(logits, stats, out, N);
}

// Round 6
// 139.745 us; speedup vs baseline: 5.6347x; 5.6347x over previous
//
#include <hip/hip_runtime.h>
#include <math.h>

// node1 [N,1,128] f32, node2 [N,32,128] f32, N=50000.
// logit[n] = dot(node1[n], sum_m node2[n,m,:]); out = softmax(logit over n).
//
// Softmax without a global-max pass: logits are ~N(0,64^2), max ~ +300, so
// exp((double)l) is safe (double overflows at 709). Per-block double partial
// sums of exp(l) -> one combine block -> logS; out = expf(l - logS).
//
// NOTE (R4 lesson): do NOT add per-block __threadfence()/atomic "last block
// done" patterns here — device-scope fences per block collapse throughput on
// CDNA4 (non-coherent per-XCD L2s): measured 140 -> 787 us.

typedef float f32x4 __attribute__((ext_vector_type(4)));

#define D4   32     // 128 floats = 32 float4 per node1 row
#define N2F4 1024   // 32*128 floats = 1024 float4 per node2 slab

// ---- Kernel 1: per-node fused sum+dot -> logits + per-block exp partials ----
// One wave (64 lanes) per node; 4 waves per 256-thread block.
__global__ __launch_bounds__(256) void logits_kernel(
    const f32x4* __restrict__ n1,    // [N][32] f32x4
    const f32x4* __restrict__ n2,    // [N][1024] f32x4
    float*  __restrict__ logits,     // [N]
    double* __restrict__ psum,       // [gridDim.x] partial sums of exp(logit)
    int N)
{
    __shared__ double se[4];
    const int wave = threadIdx.x >> 6;
    const int lane = threadIdx.x & 63;
    const int n = blockIdx.x * 4 + wave;

    double e = 0.0;
    if (n < N) {
        const f32x4* __restrict__ a = n1 + (size_t)n * D4;
        const f32x4* __restrict__ b = n2 + (size_t)n * N2F4;

        const f32x4 av = a[lane & 31];   // 64 lanes cover 32 float4s twice

        float acc = 0.0f;
#pragma unroll
        for (int i = 0; i < 16; ++i) {
            // node2 is streamed exactly once -> non-temporal
            const f32x4 bv = __builtin_nontemporal_load(&b[lane + i * 64]);
            acc += av.x * bv.x + av.y * bv.y + av.z * bv.z + av.w * bv.w;
        }

#pragma unroll
        for (int off = 32; off > 0; off >>= 1)
            acc += __shfl_down(acc, off);

        if (lane == 0) {
            logits[n] = acc;
            e = exp((double)acc);
        }
    }
    if (lane == 0) se[wave] = e;
    __syncthreads();
    if (threadIdx.x == 0)
        psum[blockIdx.x] = (se[0] + se[1]) + (se[2] + se[3]);
}

// ---- Kernel 2: sum 12500 doubles -> logS (single block, ~100 KB from L2) ----
__global__ __launch_bounds__(1024) void combine_kernel(
    const double* __restrict__ psum, double* __restrict__ stats, int nb)
{
    __shared__ double sred[16];
    const int tid  = threadIdx.x;
    const int lane = tid & 63;
    const int wid  = tid >> 6;

    double s = 0.0;
    for (int i = tid; i < nb; i += 1024) s += psum[i];
#pragma unroll
    for (int off = 32; off > 0; off >>= 1) s += __shfl_down(s, off);
    if (lane == 0) sred[wid] = s;
    __syncthreads();
    if (tid == 0) {
        double tot = 0.0;
        for (int i = 0; i < 16; ++i) tot += sred[i];
        stats[0] = log(tot);
    }
}

// ---- Kernel 3: normalize -> output ----
__global__ __launch_bounds__(256) void scale_kernel(
    const float* __restrict__ logits, const double* __restrict__ stats,
    float* __restrict__ out, int N)
{
    const float logS = (float)stats[0];
    for (int i = blockIdx.x * 256 + threadIdx.x; i < N; i += gridDim.x * 256)
        out[i] = expf(logits[i] - logS);
}

extern "C" void kernel_launch(void* const* d_in, const int* in_sizes, int n_in,
                              void* d_out, int out_size, void* d_ws, size_t ws_size,
                              hipStream_t stream)
{
    const f32x4* n1 = (const f32x4*)d_in[0];   // [N,1,128] f32
    const f32x4* n2 = (const f32x4*)d_in[1];   // [N,32,128] f32
    float* out = (float*)d_out;                // [N] f32

    const int N = out_size;                    // 50000
    const int blocks1 = (N + 3) / 4;           // 12500, one node per wave

    // ws layout: logits (N f32) | psum (blocks1 f64) | stats (1 f64)
    float*  logits = (float*)d_ws;
    char*   base   = (char*)d_ws;
    size_t  off    = ((size_t)N * sizeof(float) + 7) & ~(size_t)7;
    double* psum   = (double*)(base + off);
    double* stats  = (double*)(base + off + (size_t)blocks1 * sizeof(double));

    logits_kernel<<<blocks1, 256, 0, stream>>>(n1, n2, logits, psum, N);
    combine_kernel<<<1, 1024, 0, stream>>>(psum, stats, blocks1);
    const int blocks3 = (N + 255) / 256;
    scale_kernel<<<blocks3, 256, 0, stream>>>(logits, stats, out, N);
}